// Round 10
// baseline (446.343 us; speedup 1.0000x reference)
//
#include <hip/hip_runtime.h>
#include <hip/hip_bf16.h>
#include <math.h>
#include <stdint.h>

#define D_MODEL 1024
#define D_INNER 2048
#define D_STATE 16
#define D_CONV  4
#define DT_RANK 64
#define BATCH   2
#define SEQLEN  1024
#define M_TOK   (BATCH * SEQLEN)         // 2048 token rows
#define XDBL_W  (DT_RANK + 2 * D_STATE)  // 96
#define CHUNKS  64
#define CLEN    (SEQLEN / CHUNKS)        // 16
#define KSPLIT  32                       // x_proj split-K factor (slice = 64)
#define OSPLIT  4                        // out_proj split-K factor

typedef unsigned short us16;
typedef __bf16 bf16x8 __attribute__((ext_vector_type(8)));
typedef float floatx4 __attribute__((ext_vector_type(4)));

__device__ __forceinline__ float silu_f(float v) {
    return v / (1.0f + __expf(-v));
}
__device__ __forceinline__ float softplus_f(float v) {
    return v > 20.0f ? v : log1pf(__expf(v));
}
__device__ __forceinline__ us16 f2bf(float f) {   // round-to-nearest-even
    unsigned u = __float_as_uint(f);
    u += 0x7FFF + ((u >> 16) & 1);
    return (us16)(u >> 16);
}
__device__ __forceinline__ float bf2f(us16 h) {
    return __uint_as_float(((unsigned)h) << 16);
}

// async 16B global -> LDS (dest = wave-uniform base + lane*16)
__device__ __forceinline__ void gload_lds16(const us16* g, us16* l) {
    auto* l3 = reinterpret_cast<__attribute__((address_space(3))) us16*>(
        reinterpret_cast<uintptr_t>(l));
    auto* g1 = reinterpret_cast<const __attribute__((address_space(1))) us16*>(
        reinterpret_cast<uintptr_t>(g));
    __builtin_amdgcn_global_load_lds(g1, l3, 16, 0, 0);
}

// zero-init out (8MB) + xdbl (0.75MB) for the atomic accumulators
__global__ __launch_bounds__(256)
void zero_kernel(float* __restrict__ out, float* __restrict__ xdbl)
{
    const int b = blockIdx.x;
    if (b < 2048) {
        const int i = (b * 256 + threadIdx.x) * 4;
        *(float4*)(out + i) = make_float4(0.f, 0.f, 0.f, 0.f);
    } else {
        const int i = ((b - 2048) * 256 + threadIdx.x) * 4;
        *(float4*)(xdbl + i) = make_float4(0.f, 0.f, 0.f, 0.f);
    }
}

// One fused split kernel: hs (2048 blocks) + in_w (4096) + out_w (2048).
__global__ __launch_bounds__(256)
void split_all(const float* __restrict__ hs, const float* __restrict__ iw,
               const float* __restrict__ ow,
               us16* __restrict__ hsh, us16* __restrict__ hsl,
               us16* __restrict__ iwh, us16* __restrict__ iwl,
               us16* __restrict__ owh, us16* __restrict__ owl)
{
    const int b = blockIdx.x;
    const float* src;
    us16 *hi, *lo;
    int rel;
    if (b < 2048)      { src = hs; hi = hsh; lo = hsl; rel = b; }
    else if (b < 6144) { src = iw; hi = iwh; lo = iwl; rel = b - 2048; }
    else               { src = ow; hi = owh; lo = owl; rel = b - 6144; }
    const int i = (rel * 256 + threadIdx.x) * 4;
    const float4 v = *(const float4*)(src + i);
    us16 h0 = f2bf(v.x), h1 = f2bf(v.y), h2 = f2bf(v.z), h3 = f2bf(v.w);
    ushort4 hv = {h0, h1, h2, h3};
    ushort4 lv = {f2bf(v.x - bf2f(h0)), f2bf(v.y - bf2f(h1)),
                  f2bf(v.z - bf2f(h2)), f2bf(v.w - bf2f(h3))};
    *(ushort4*)(hi + i) = hv;
    *(ushort4*)(lo + i) = lv;
}

// ---------------- fused split-bf16 MFMA GEMM (16x16x32) ----------------
// C[m,n] = sum_k A[m,k]*W[n,k], 3-product split (Ah*Wh + Al*Wh + Ah*Wl)
// fused per K-tile. BM=128, BN=128, BK=32, 256 threads = 4 waves (2x2),
// 48 MFMA/barrier/wave — R9 A/B confirmed this beats BN=64's higher TLP.
// LDS rows XOR-swizzled (16B chunk pos ^= (row>>1)&3) -> 0 bank conflicts.
// MODE 1: in_proj x/z split (col < D_INNER -> C0 else C1), ldc = D_INNER.
// MODE 2: split-K out_proj — atomicAdd into C0[row*ldc + col].
template<int BN, int MODE>
__global__ __launch_bounds__(256)
void gemm_mfma3(const us16* __restrict__ Ah, const us16* __restrict__ Al,
                const us16* __restrict__ Wh, const us16* __restrict__ Wl,
                int lda, int kLen, float* __restrict__ C0,
                float* __restrict__ C1, int ldc)
{
    constexpr int BM = 128;
    constexpr int NT = BN / 32;          // n-tiles per wave (128->4)
    __shared__ us16 sAh[BM * 32];
    __shared__ us16 sAl[BM * 32];
    __shared__ us16 sWh[BN * 32];
    __shared__ us16 sWl[BN * 32];

    const int tid  = threadIdx.x;
    const int wave = tid >> 6;
    const int lane = tid & 63;
    const int wm   = wave & 1;
    const int wn   = wave >> 1;
    const int m0   = blockIdx.y * BM;
    const int n0   = blockIdx.x * BN;
    const int kBeg = blockIdx.z * kLen;
    const int quad = lane >> 4;
    const int l15  = lane & 15;
    const int sr   = lane >> 2;          // row within a 16-row slab
    const int spos = lane & 3;           // 16B chunk position in 64B row

    floatx4 acc[4][NT] = {};

    for (int k0 = 0; k0 < kLen; k0 += 32) {
        __syncthreads();   // previous iteration's LDS readers done
        // --- stage A hi+lo (8 slabs of 16 rows; wave w does slabs w, w+4)
        {
            int s = wave;
            int row = s * 16 + sr;
            int c = spos ^ ((row >> 1) & 3);
            size_t go = (size_t)(m0 + row) * lda + kBeg + k0 + c * 8;
            gload_lds16(Ah + go, sAh + s * 512);
            gload_lds16(Al + go, sAl + s * 512);
            s = wave + 4;
            row = s * 16 + sr;
            c = spos ^ ((row >> 1) & 3);
            go = (size_t)(m0 + row) * lda + kBeg + k0 + c * 8;
            gload_lds16(Ah + go, sAh + s * 512);
            gload_lds16(Al + go, sAl + s * 512);
        }
        // --- stage W hi+lo
        {
            int s = wave;
            int row = s * 16 + sr;
            int c = spos ^ ((row >> 1) & 3);
            size_t go = (size_t)(n0 + row) * lda + kBeg + k0 + c * 8;
            gload_lds16(Wh + go, sWh + s * 512);
            gload_lds16(Wl + go, sWl + s * 512);
            s = wave + 4;
            row = s * 16 + sr;
            c = spos ^ ((row >> 1) & 3);
            go = (size_t)(n0 + row) * lda + kBeg + k0 + c * 8;
            gload_lds16(Wh + go, sWh + s * 512);
            gload_lds16(Wl + go, sWl + s * 512);
        }
        __syncthreads();   // drain global_load_lds

        bf16x8 ah[4], al[4], bh[NT], bl[NT];
#pragma unroll
        for (int i = 0; i < 4; i++) {
            const int r = wm * 64 + i * 16 + l15;
            const int off = r * 32 + ((quad ^ ((r >> 1) & 3)) * 8);
            ah[i] = *(const bf16x8*)(sAh + off);
            al[i] = *(const bf16x8*)(sAl + off);
        }
#pragma unroll
        for (int j = 0; j < NT; j++) {
            const int r = wn * (BN / 2) + j * 16 + l15;
            const int off = r * 32 + ((quad ^ ((r >> 1) & 3)) * 8);
            bh[j] = *(const bf16x8*)(sWh + off);
            bl[j] = *(const bf16x8*)(sWl + off);
        }
#pragma unroll
        for (int i = 0; i < 4; i++)
#pragma unroll
            for (int j = 0; j < NT; j++) {
                acc[i][j] = __builtin_amdgcn_mfma_f32_16x16x32_bf16(
                    ah[i], bh[j], acc[i][j], 0, 0, 0);
                acc[i][j] = __builtin_amdgcn_mfma_f32_16x16x32_bf16(
                    al[i], bh[j], acc[i][j], 0, 0, 0);
                acc[i][j] = __builtin_amdgcn_mfma_f32_16x16x32_bf16(
                    ah[i], bl[j], acc[i][j], 0, 0, 0);
            }
    }

    // epilogue: C/D layout col=lane&15, row=quad*4+reg
#pragma unroll
    for (int i = 0; i < 4; i++) {
        const int rowb = m0 + wm * 64 + i * 16 + quad * 4;
#pragma unroll
        for (int j = 0; j < NT; j++) {
            const int col = n0 + wn * (BN / 2) + j * 16 + l15;
#pragma unroll
            for (int r = 0; r < 4; r++) {
                const float v = acc[i][j][r];
                const size_t rr = (size_t)(rowb + r);
                if (MODE == 1) {
                    if (n0 < D_INNER) C0[rr * D_INNER + col] = v;
                    else              C1[rr * D_INNER + (col - D_INNER)] = v;
                } else {
                    atomicAdd(&C0[rr * ldc + col], v);
                }
            }
        }
    }
}

// ---------------- fp32 tile GEMM: dt_proj ----------------
__global__ __launch_bounds__(256)
void gemm_dt(const float* __restrict__ A, int lda,
             const float* __restrict__ W, int ldw,
             float* __restrict__ C0, int ldc,
             const float* __restrict__ bias, int K)
{
    __shared__ float As[16][68];
    __shared__ float Ws[16][68];

    const int tid  = threadIdx.x;
    const int tx   = tid & 15;
    const int ty   = tid >> 4;
    const int n0   = blockIdx.x * 64;
    const int m0   = blockIdx.y * 64;
    const int lrow = tid >> 2;
    const int lkq  = tid & 3;

    float acc[4][4] = {};

    for (int k0 = 0; k0 < K; k0 += 16) {
        const float4 av = *(const float4*)(A + (size_t)(m0 + lrow) * lda + k0 + lkq * 4);
        const float4 wv = *(const float4*)(W + (size_t)(n0 + lrow) * ldw + k0 + lkq * 4);

        __syncthreads();
        As[lkq * 4 + 0][lrow] = av.x;
        As[lkq * 4 + 1][lrow] = av.y;
        As[lkq * 4 + 2][lrow] = av.z;
        As[lkq * 4 + 3][lrow] = av.w;
        Ws[lkq * 4 + 0][lrow] = wv.x;
        Ws[lkq * 4 + 1][lrow] = wv.y;
        Ws[lkq * 4 + 2][lrow] = wv.z;
        Ws[lkq * 4 + 3][lrow] = wv.w;
        __syncthreads();

#pragma unroll
        for (int k = 0; k < 16; k++) {
            const float4 a = *(const float4*)&As[k][ty * 4];
            const float4 w = *(const float4*)&Ws[k][tx * 4];
            const float avv[4] = {a.x, a.y, a.z, a.w};
            const float wvv[4] = {w.x, w.y, w.z, w.w};
#pragma unroll
            for (int i = 0; i < 4; i++)
#pragma unroll
                for (int j = 0; j < 4; j++)
                    acc[i][j] += avv[i] * wvv[j];
        }
    }

    const int mbase = m0 + ty * 4;
    const int nbase = n0 + tx * 4;
#pragma unroll
    for (int i = 0; i < 4; i++)
#pragma unroll
        for (int j = 0; j < 4; j++) {
            const int n = nbase + j;
            C0[(size_t)(mbase + i) * ldc + n] = softplus_f(acc[i][j] + bias[n]);
        }
}

// x_proj split-K, single 96-wide column tile (conv computed once per (m,d,kz)):
// A[m][d] = silu(conv_b[d] + sum_k conv_w[d][k] * x[m-3+k][d]).
// grid (M/64, KSPLIT); K slice = D_INNER/KSPLIT = 64. Microtile 4m x 6n.
// Epilogue: atomicAdd into pre-zeroed xdbl (no partial buffer / reduce pass).
__global__ __launch_bounds__(256)
void gemm_xproj(const float* __restrict__ xg, const float* __restrict__ conv_w,
                const float* __restrict__ conv_b,
                const float* __restrict__ W, float* __restrict__ xdbl)
{
    __shared__ float As[16][68];
    __shared__ float Ws[16][100];

    const int tid  = threadIdx.x;
    const int tx   = tid & 15;      // n-dir, 6 cols each
    const int ty   = tid >> 4;      // m-dir, 4 rows each
    const int m0   = blockIdx.x * 64;
    const int kz   = blockIdx.y;
    const int lrow = tid >> 2;
    const int lkq  = tid & 3;

    const float4* cw = (const float4*)conv_w;   // cw[d] = taps of channel d
    const float4* cb = (const float4*)conv_b;

    float acc[4][6] = {};
    const int kbeg = kz * (D_INNER / KSPLIT);
    const int kend = kbeg + (D_INNER / KSPLIT);

    const int m = m0 + lrow;
    const int t = m & (SEQLEN - 1);

    for (int k0 = kbeg; k0 < kend; k0 += 16) {
        const int dcol = k0 + lkq * 4;
        // conv + silu for A[m][dcol..dcol+3]
        const float4 w0 = cw[dcol], w1 = cw[dcol + 1], w2 = cw[dcol + 2], w3 = cw[dcol + 3];
        float4 a = cb[dcol >> 2];
        const float* xr = xg + (size_t)m * D_INNER + dcol;
        {
            float4 xk;
            if (t >= 3) { xk = *(const float4*)(xr - 3 * D_INNER);
                a.x += w0.x * xk.x; a.y += w1.x * xk.y; a.z += w2.x * xk.z; a.w += w3.x * xk.w; }
            if (t >= 2) { xk = *(const float4*)(xr - 2 * D_INNER);
                a.x += w0.y * xk.x; a.y += w1.y * xk.y; a.z += w2.y * xk.z; a.w += w3.y * xk.w; }
            if (t >= 1) { xk = *(const float4*)(xr - 1 * D_INNER);
                a.x += w0.z * xk.x; a.y += w1.z * xk.y; a.z += w2.z * xk.z; a.w += w3.z * xk.w; }
            xk = *(const float4*)(xr);
            a.x += w0.w * xk.x; a.y += w1.w * xk.y; a.z += w2.w * xk.z; a.w += w3.w * xk.w;
        }
        const float4 av = make_float4(silu_f(a.x), silu_f(a.y), silu_f(a.z), silu_f(a.w));

        // W rows 0..63 staged by all threads; rows 64..95 by threads < 128
        const float4 wv = *(const float4*)(W + (size_t)lrow * D_INNER + k0 + lkq * 4);
        float4 wv2 = make_float4(0.f, 0.f, 0.f, 0.f);
        if (tid < 128)
            wv2 = *(const float4*)(W + (size_t)(64 + lrow) * D_INNER + k0 + lkq * 4);

        __syncthreads();
        As[lkq * 4 + 0][lrow] = av.x;
        As[lkq * 4 + 1][lrow] = av.y;
        As[lkq * 4 + 2][lrow] = av.z;
        As[lkq * 4 + 3][lrow] = av.w;
        Ws[lkq * 4 + 0][lrow] = wv.x;
        Ws[lkq * 4 + 1][lrow] = wv.y;
        Ws[lkq * 4 + 2][lrow] = wv.z;
        Ws[lkq * 4 + 3][lrow] = wv.w;
        if (tid < 128) {
            Ws[lkq * 4 + 0][64 + lrow] = wv2.x;
            Ws[lkq * 4 + 1][64 + lrow] = wv2.y;
            Ws[lkq * 4 + 2][64 + lrow] = wv2.z;
            Ws[lkq * 4 + 3][64 + lrow] = wv2.w;
        }
        __syncthreads();

#pragma unroll
        for (int k = 0; k < 16; k++) {
            const float4 a4 = *(const float4*)&As[k][ty * 4];
            const float avv[4] = {a4.x, a4.y, a4.z, a4.w};
            float wvv[6];
#pragma unroll
            for (int j = 0; j < 6; j++) wvv[j] = Ws[k][tx * 6 + j];
#pragma unroll
            for (int i = 0; i < 4; i++)
#pragma unroll
                for (int j = 0; j < 6; j++)
                    acc[i][j] += avv[i] * wvv[j];
        }
    }

    const int mbase = m0 + ty * 4;
    const int nbase = tx * 6;
#pragma unroll
    for (int i = 0; i < 4; i++)
#pragma unroll
        for (int j = 0; j < 6; j++)
            atomicAdd(&xdbl[(size_t)(mbase + i) * XDBL_W + nbase + j], acc[i][j]);
}

// ---------- chunk-parallel selective scan (CHUNKS=64, CLEN=16) ----------
// u = silu(conv(x)+b) recomputed inline via rolling 4-tap window.
// Phase 1: per-chunk decay product P[n] and zero-init partial state S[n].
// Layout of P/S/H: [b][c][n][d] (d-coalesced).
__global__ __launch_bounds__(256)
void scan_part(const float* __restrict__ delta, const float* __restrict__ xdbl,
               const float* __restrict__ xg, const float* __restrict__ conv_w,
               const float* __restrict__ conv_b, const float* __restrict__ A_log,
               float* __restrict__ P, float* __restrict__ S)
{
    const int g = blockIdx.x * 256 + threadIdx.x;   // 262144 total
    const int d = g & (D_INNER - 1);
    const int c = (g >> 11) & (CHUNKS - 1);
    const int b = g >> 17;

    float An[D_STATE];
#pragma unroll
    for (int n = 0; n < D_STATE; n++)
        An[n] = -__expf(A_log[d * D_STATE + n]);

    const float4 wd = ((const float4*)conv_w)[d];
    const float cb = conv_b[d];

    float p[D_STATE], s[D_STATE];
#pragma unroll
    for (int n = 0; n < D_STATE; n++) { p[n] = 1.f; s[n] = 0.f; }

    const size_t row0 = (size_t)b * SEQLEN + c * CLEN;
    const float* xp = xg + row0 * D_INNER + d;
    float xm3 = 0.f, xm2 = 0.f, xm1 = 0.f;
    if (c > 0) {
        xm3 = xp[-3 * D_INNER];
        xm2 = xp[-2 * D_INNER];
        xm1 = xp[-1 * D_INNER];
    }

#pragma unroll 4
    for (int t = 0; t < CLEN; t++) {
        const size_t row = row0 + t;
        const float xm0 = xp[(size_t)t * D_INNER];
        const float u   = silu_f(cb + wd.x * xm3 + wd.y * xm2 + wd.z * xm1 + wd.w * xm0);
        xm3 = xm2; xm2 = xm1; xm1 = xm0;
        const float dlt  = delta[row * D_INNER + d];
        const float dltu = dlt * u;
        const float4* Bp = (const float4*)(xdbl + row * XDBL_W + DT_RANK);
        const float4 B0 = Bp[0], B1 = Bp[1], B2 = Bp[2], B3 = Bp[3];
        const float Bv[D_STATE] = {B0.x, B0.y, B0.z, B0.w, B1.x, B1.y, B1.z, B1.w,
                                   B2.x, B2.y, B2.z, B2.w, B3.x, B3.y, B3.z, B3.w};
#pragma unroll
        for (int n = 0; n < D_STATE; n++) {
            const float a = __expf(dlt * An[n]);
            s[n] = s[n] * a + dltu * Bv[n];
            p[n] *= a;
        }
    }

    const size_t base = ((size_t)(b * CHUNKS + c) * D_STATE) * D_INNER + d;
#pragma unroll
    for (int n = 0; n < D_STATE; n++) {
        P[base + (size_t)n * D_INNER] = p[n];
        S[base + (size_t)n * D_INNER] = s[n];
    }
}

// Phase 1.5: serial cross-chunk combine per (b,n,d); converts P (in-place!)
// into H = chunk-entry states: H[c] = S[c-1] + P[c-1]*H[c-1], H[0]=0.
__global__ __launch_bounds__(256)
void scan_prefix(float* PH, const float* __restrict__ S)
{
    const int g = blockIdx.x * 256 + threadIdx.x;   // 65536 total
    const int d = g & (D_INNER - 1);
    const int n = (g >> 11) & (D_STATE - 1);
    const int b = g >> 15;

    float h = 0.f;
    for (int c = 0; c < CHUNKS; c++) {
        const size_t idx = ((size_t)(b * CHUNKS + c) * D_STATE + n) * D_INNER + d;
        const float p = PH[idx];
        const float s = S[idx];
        PH[idx] = h;
        h = s + p * h;
    }
}

// Phase 2: load chunk-entry state from H, replay chunk (inline conv for u),
// skip + z-gate, emit y as bf16 hi/lo for out_proj's A operand.
__global__ __launch_bounds__(256)
void scan_apply(const float* __restrict__ delta, const float* __restrict__ xdbl,
                const float* __restrict__ xg, const float* __restrict__ conv_w,
                const float* __restrict__ conv_b, const float* __restrict__ A_log,
                const float* __restrict__ D_skip,
                const float* __restrict__ H,
                const float* __restrict__ z,
                us16* __restrict__ yh, us16* __restrict__ yl)
{
    const int g = blockIdx.x * 256 + threadIdx.x;
    const int d = g & (D_INNER - 1);
    const int c = (g >> 11) & (CHUNKS - 1);
    const int b = g >> 17;

    float An[D_STATE];
#pragma unroll
    for (int n = 0; n < D_STATE; n++)
        An[n] = -__expf(A_log[d * D_STATE + n]);

    const float4 wd = ((const float4*)conv_w)[d];
    const float cb = conv_b[d];

    float st[D_STATE];
    const size_t hbase = ((size_t)(b * CHUNKS + c) * D_STATE) * D_INNER + d;
#pragma unroll
    for (int n = 0; n < D_STATE; n++)
        st[n] = H[hbase + (size_t)n * D_INNER];

    const float Dv = D_skip[d];
    const size_t row0 = (size_t)b * SEQLEN + c * CLEN;
    const float* xp = xg + row0 * D_INNER + d;
    float xm3 = 0.f, xm2 = 0.f, xm1 = 0.f;
    if (c > 0) {
        xm3 = xp[-3 * D_INNER];
        xm2 = xp[-2 * D_INNER];
        xm1 = xp[-1 * D_INNER];
    }

#pragma unroll 4
    for (int t = 0; t < CLEN; t++) {
        const size_t row = row0 + t;
        const float xm0 = xp[(size_t)t * D_INNER];
        const float u   = silu_f(cb + wd.x * xm3 + wd.y * xm2 + wd.z * xm1 + wd.w * xm0);
        xm3 = xm2; xm2 = xm1; xm1 = xm0;
        const float dlt  = delta[row * D_INNER + d];
        const float dltu = dlt * u;
        const float4* Bp = (const float4*)(xdbl + row * XDBL_W + DT_RANK);
        const float4 B0 = Bp[0], B1 = Bp[1], B2 = Bp[2], B3 = Bp[3];
        const float4* Cp = (const float4*)(xdbl + row * XDBL_W + DT_RANK + D_STATE);
        const float4 C0 = Cp[0], C1 = Cp[1], C2 = Cp[2], C3 = Cp[3];
        const float Bv[D_STATE] = {B0.x, B0.y, B0.z, B0.w, B1.x, B1.y, B1.z, B1.w,
                                   B2.x, B2.y, B2.z, B2.w, B3.x, B3.y, B3.z, B3.w};
        const float Cv[D_STATE] = {C0.x, C0.y, C0.z, C0.w, C1.x, C1.y, C1.z, C1.w,
                                   C2.x, C2.y, C2.z, C2.w, C3.x, C3.y, C3.z, C3.w};
        float y = 0.f;
#pragma unroll
        for (int n = 0; n < D_STATE; n++) {
            const float a = __expf(dlt * An[n]);
            st[n] = st[n] * a + dltu * Bv[n];
            y += st[n] * Cv[n];
        }
        const float yv = (y + u * Dv) * silu_f(z[row * D_INNER + d]);
        const us16 h = f2bf(yv);
        yh[row * D_INNER + d] = h;
        yl[row * D_INNER + d] = f2bf(yv - bf2f(h));
    }
}

extern "C" void kernel_launch(void* const* d_in, const int* in_sizes, int n_in,
                              void* d_out, int out_size, void* d_ws, size_t ws_size,
                              hipStream_t stream)
{
    const float* hs         = (const float*)d_in[0];
    const float* in_proj_w  = (const float*)d_in[1];
    const float* conv_w     = (const float*)d_in[2];
    const float* conv_b     = (const float*)d_in[3];
    const float* x_proj_w   = (const float*)d_in[4];
    const float* dt_proj_w  = (const float*)d_in[5];
    const float* dt_proj_b  = (const float*)d_in[6];
    const float* A_log      = (const float*)d_in[7];
    const float* D_skip     = (const float*)d_in[8];
    const float* out_proj_w = (const float*)d_in[9];
    float* out = (float*)d_out;

    // Phase-aliased workspace (89 MB). Liveness:
    //   [ 0-16)  x      (step2 -> scan_apply)
    //   [16-32)  z      (step2 -> scan_apply)
    //   [32-48)  delta  (step4 -> scan_apply)
    //   [48-49)  xdbl   (step3 atomic accum -> scan_apply)
    //   [49-65)  iwh/iwl (step1->2); Pbuf/H (5a->5c)
    //   [65-81)  hsh/hsl (step1->2); Sbuf (5a->5b); ybh/ybl (5c->6)
    //   [81-89)  owh/owl (step1->6)
    char* base = (char*)d_ws;
    const size_t MB = 1u << 20;
    float* xbuf  = (float*)(base);
    float* zbuf  = (float*)(base + 16 * MB);
    float* dbuf  = (float*)(base + 32 * MB);   // delta
    float* xdbl  = (float*)(base + 48 * MB);
    us16*  iwh   = (us16*)(base + 49 * MB);
    us16*  iwl   = (us16*)(base + 57 * MB);
    float* Pbuf  = (float*)(base + 49 * MB);   // scan P/H (iw dead)
    us16*  hsh   = (us16*)(base + 65 * MB);
    us16*  hsl   = (us16*)(base + 69 * MB);
    float* Sbuf  = (float*)(base + 65 * MB);   // scan S (hs dead)
    us16*  ybh   = (us16*)(base + 65 * MB);    // y hi (S dead after prefix)
    us16*  ybl   = (us16*)(base + 73 * MB);
    us16*  owh   = (us16*)(base + 81 * MB);
    us16*  owl   = (us16*)(base + 85 * MB);

    const dim3 blk(256);

    // 0. zero the atomic accumulators: out (8MB) + xdbl (0.75MB)
    zero_kernel<<<2048 + (M_TOK * XDBL_W) / 1024, blk, 0, stream>>>(out, xdbl);

    // 1. one fused split: hs + in_proj_w + out_proj_w -> bf16 hi/lo
    split_all<<<8192, blk, 0, stream>>>(hs, in_proj_w, out_proj_w,
                                        hsh, hsl, iwh, iwl, owh, owl);

    // 2. in_proj (fused 3-product MFMA, BM=BN=128): xz -> x, z
    gemm_mfma3<128, 1><<<dim3((2 * D_INNER) / 128, M_TOK / 128), blk, 0, stream>>>(
        hsh, hsl, iwh, iwl, D_MODEL, D_MODEL, xbuf, zbuf, D_INNER);

    // 3. x_proj split-K=32, single 96-col tile (conv inlined), atomic accum
    gemm_xproj<<<dim3(M_TOK / 64, KSPLIT), blk, 0, stream>>>(
        xbuf, conv_w, conv_b, x_proj_w, xdbl);

    // 4. dt_proj + softplus -> delta
    gemm_dt<<<dim3(D_INNER / 64, M_TOK / 64), blk, 0, stream>>>(
        xdbl, XDBL_W, dt_proj_w, DT_RANK, dbuf, D_INNER, dt_proj_b, DT_RANK);

    // 5. chunk-parallel scan (conv inlined): part -> prefix -> apply
    scan_part<<<(BATCH * CHUNKS * D_INNER) / 256, blk, 0, stream>>>(
        dbuf, xdbl, xbuf, conv_w, conv_b, A_log, Pbuf, Sbuf);
    scan_prefix<<<(BATCH * D_STATE * D_INNER) / 256, blk, 0, stream>>>(
        Pbuf, Sbuf);
    scan_apply<<<(BATCH * CHUNKS * D_INNER) / 256, blk, 0, stream>>>(
        dbuf, xdbl, xbuf, conv_w, conv_b, A_log, D_skip, Pbuf, zbuf, ybh, ybl);

    // 6. out_proj (fused 3-product MFMA, BM=BN=128, split-K=4, atomic accum)
    gemm_mfma3<128, 2><<<dim3(D_MODEL / 128, M_TOK / 128, OSPLIT), blk, 0, stream>>>(
        ybh, ybl, owh, owl, D_INNER, D_INNER / OSPLIT, out, nullptr, D_MODEL);
}

// Round 11
// 313.500 us; speedup vs baseline: 1.4237x; 1.4237x over previous
//
#include <hip/hip_runtime.h>
#include <hip/hip_bf16.h>
#include <math.h>
#include <stdint.h>

#define D_MODEL 1024
#define D_INNER 2048
#define D_STATE 16
#define D_CONV  4
#define DT_RANK 64
#define BATCH   2
#define SEQLEN  1024
#define M_TOK   (BATCH * SEQLEN)         // 2048 token rows
#define XDBL_W  (DT_RANK + 2 * D_STATE)  // 96
#define CHUNKS  64
#define CLEN    (SEQLEN / CHUNKS)        // 16
#define KSPLIT  32                       // x_proj split-K factor (slice = 64)
#define OSPLIT  4                        // out_proj split-K factor

typedef unsigned short us16;
typedef __bf16 bf16x8 __attribute__((ext_vector_type(8)));
typedef float floatx4 __attribute__((ext_vector_type(4)));

__device__ __forceinline__ float silu_f(float v) {
    return v / (1.0f + __expf(-v));
}
__device__ __forceinline__ float softplus_f(float v) {
    return v > 20.0f ? v : log1pf(__expf(v));
}
__device__ __forceinline__ us16 f2bf(float f) {   // round-to-nearest-even
    unsigned u = __float_as_uint(f);
    u += 0x7FFF + ((u >> 16) & 1);
    return (us16)(u >> 16);
}
__device__ __forceinline__ float bf2f(us16 h) {
    return __uint_as_float(((unsigned)h) << 16);
}

// async 16B global -> LDS (dest = wave-uniform base + lane*16)
__device__ __forceinline__ void gload_lds16(const us16* g, us16* l) {
    auto* l3 = reinterpret_cast<__attribute__((address_space(3))) us16*>(
        reinterpret_cast<uintptr_t>(l));
    auto* g1 = reinterpret_cast<const __attribute__((address_space(1))) us16*>(
        reinterpret_cast<uintptr_t>(g));
    __builtin_amdgcn_global_load_lds(g1, l3, 16, 0, 0);
}

// One fused split kernel: hs (2048 blocks) + in_w (4096) + out_w (2048).
__global__ __launch_bounds__(256)
void split_all(const float* __restrict__ hs, const float* __restrict__ iw,
               const float* __restrict__ ow,
               us16* __restrict__ hsh, us16* __restrict__ hsl,
               us16* __restrict__ iwh, us16* __restrict__ iwl,
               us16* __restrict__ owh, us16* __restrict__ owl)
{
    const int b = blockIdx.x;
    const float* src;
    us16 *hi, *lo;
    int rel;
    if (b < 2048)      { src = hs; hi = hsh; lo = hsl; rel = b; }
    else if (b < 6144) { src = iw; hi = iwh; lo = iwl; rel = b - 2048; }
    else               { src = ow; hi = owh; lo = owl; rel = b - 6144; }
    const int i = (rel * 256 + threadIdx.x) * 4;
    const float4 v = *(const float4*)(src + i);
    us16 h0 = f2bf(v.x), h1 = f2bf(v.y), h2 = f2bf(v.z), h3 = f2bf(v.w);
    ushort4 hv = {h0, h1, h2, h3};
    ushort4 lv = {f2bf(v.x - bf2f(h0)), f2bf(v.y - bf2f(h1)),
                  f2bf(v.z - bf2f(h2)), f2bf(v.w - bf2f(h3))};
    *(ushort4*)(hi + i) = hv;
    *(ushort4*)(lo + i) = lv;
}

// ---------------- fused split-bf16 MFMA GEMM (16x16x32) ----------------
// C[m,n] = sum_k A[m,k]*W[n,k], 3-product split (Ah*Wh + Al*Wh + Ah*Wl)
// fused per K-tile. BM=128, BN=128, BK=32, 256 threads = 4 waves (2x2),
// 48 MFMA/barrier/wave — R9 A/B: this beats BN=64's higher TLP.
// R10 A/B: partial-store + reduce beats atomicAdd epilogue (6x less traffic).
// LDS rows XOR-swizzled (16B chunk pos ^= (row>>1)&3) -> 0 bank conflicts.
// MODE 1: in_proj x/z split (col < D_INNER -> C0 else C1), ldc = D_INNER.
// MODE 2: partial store C0[(z*M_TOK+row)*ldc + col] (split-K out_proj).
template<int BN, int MODE>
__global__ __launch_bounds__(256)
void gemm_mfma3(const us16* __restrict__ Ah, const us16* __restrict__ Al,
                const us16* __restrict__ Wh, const us16* __restrict__ Wl,
                int lda, int kLen, float* __restrict__ C0,
                float* __restrict__ C1, int ldc)
{
    constexpr int BM = 128;
    constexpr int NT = BN / 32;          // n-tiles per wave (128->4)
    __shared__ us16 sAh[BM * 32];
    __shared__ us16 sAl[BM * 32];
    __shared__ us16 sWh[BN * 32];
    __shared__ us16 sWl[BN * 32];

    const int tid  = threadIdx.x;
    const int wave = tid >> 6;
    const int lane = tid & 63;
    const int wm   = wave & 1;
    const int wn   = wave >> 1;
    const int m0   = blockIdx.y * BM;
    const int n0   = blockIdx.x * BN;
    const int kBeg = blockIdx.z * kLen;
    const int quad = lane >> 4;
    const int l15  = lane & 15;
    const int sr   = lane >> 2;          // row within a 16-row slab
    const int spos = lane & 3;           // 16B chunk position in 64B row

    floatx4 acc[4][NT] = {};

    for (int k0 = 0; k0 < kLen; k0 += 32) {
        __syncthreads();   // previous iteration's LDS readers done
        // --- stage A hi+lo (8 slabs of 16 rows; wave w does slabs w, w+4)
        {
            int s = wave;
            int row = s * 16 + sr;
            int c = spos ^ ((row >> 1) & 3);
            size_t go = (size_t)(m0 + row) * lda + kBeg + k0 + c * 8;
            gload_lds16(Ah + go, sAh + s * 512);
            gload_lds16(Al + go, sAl + s * 512);
            s = wave + 4;
            row = s * 16 + sr;
            c = spos ^ ((row >> 1) & 3);
            go = (size_t)(m0 + row) * lda + kBeg + k0 + c * 8;
            gload_lds16(Ah + go, sAh + s * 512);
            gload_lds16(Al + go, sAl + s * 512);
        }
        // --- stage W hi+lo
        {
            int s = wave;
            int row = s * 16 + sr;
            int c = spos ^ ((row >> 1) & 3);
            size_t go = (size_t)(n0 + row) * lda + kBeg + k0 + c * 8;
            gload_lds16(Wh + go, sWh + s * 512);
            gload_lds16(Wl + go, sWl + s * 512);
            if (BN == 128) {
                s = wave + 4;
                row = s * 16 + sr;
                c = spos ^ ((row >> 1) & 3);
                go = (size_t)(n0 + row) * lda + kBeg + k0 + c * 8;
                gload_lds16(Wh + go, sWh + s * 512);
                gload_lds16(Wl + go, sWl + s * 512);
            }
        }
        __syncthreads();   // drain global_load_lds

        bf16x8 ah[4], al[4], bh[NT], bl[NT];
#pragma unroll
        for (int i = 0; i < 4; i++) {
            const int r = wm * 64 + i * 16 + l15;
            const int off = r * 32 + ((quad ^ ((r >> 1) & 3)) * 8);
            ah[i] = *(const bf16x8*)(sAh + off);
            al[i] = *(const bf16x8*)(sAl + off);
        }
#pragma unroll
        for (int j = 0; j < NT; j++) {
            const int r = wn * (BN / 2) + j * 16 + l15;
            const int off = r * 32 + ((quad ^ ((r >> 1) & 3)) * 8);
            bh[j] = *(const bf16x8*)(sWh + off);
            bl[j] = *(const bf16x8*)(sWl + off);
        }
#pragma unroll
        for (int i = 0; i < 4; i++)
#pragma unroll
            for (int j = 0; j < NT; j++) {
                acc[i][j] = __builtin_amdgcn_mfma_f32_16x16x32_bf16(
                    ah[i], bh[j], acc[i][j], 0, 0, 0);
                acc[i][j] = __builtin_amdgcn_mfma_f32_16x16x32_bf16(
                    al[i], bh[j], acc[i][j], 0, 0, 0);
                acc[i][j] = __builtin_amdgcn_mfma_f32_16x16x32_bf16(
                    ah[i], bl[j], acc[i][j], 0, 0, 0);
            }
    }

    // epilogue: C/D layout col=lane&15, row=quad*4+reg
#pragma unroll
    for (int i = 0; i < 4; i++) {
        const int rowb = m0 + wm * 64 + i * 16 + quad * 4;
#pragma unroll
        for (int j = 0; j < NT; j++) {
            const int col = n0 + wn * (BN / 2) + j * 16 + l15;
#pragma unroll
            for (int r = 0; r < 4; r++) {
                const float v = acc[i][j][r];
                const size_t rr = (size_t)(rowb + r);
                if (MODE == 1) {
                    if (n0 < D_INNER) C0[rr * D_INNER + col] = v;
                    else              C1[rr * D_INNER + (col - D_INNER)] = v;
                } else {
                    C0[((size_t)blockIdx.z * M_TOK + rr) * ldc + col] = v;
                }
            }
        }
    }
}

// out = sum of OSPLIT partials, float4 per thread
__global__ __launch_bounds__(256)
void add4_kernel(const float* __restrict__ part, float* __restrict__ out)
{
    const int i = (blockIdx.x * 256 + threadIdx.x) * 4;
    const size_t stride = (size_t)M_TOK * D_MODEL;
    float4 a = *(const float4*)(part + i);
#pragma unroll
    for (int k = 1; k < OSPLIT; k++) {
        const float4 b = *(const float4*)(part + k * stride + i);
        a.x += b.x; a.y += b.y; a.z += b.z; a.w += b.w;
    }
    *(float4*)(out + i) = a;
}

// ---------------- fp32 tile GEMM: dt_proj ----------------
__global__ __launch_bounds__(256)
void gemm_dt(const float* __restrict__ A, int lda,
             const float* __restrict__ W, int ldw,
             float* __restrict__ C0, int ldc,
             const float* __restrict__ bias, int K)
{
    __shared__ float As[16][68];
    __shared__ float Ws[16][68];

    const int tid  = threadIdx.x;
    const int tx   = tid & 15;
    const int ty   = tid >> 4;
    const int n0   = blockIdx.x * 64;
    const int m0   = blockIdx.y * 64;
    const int lrow = tid >> 2;
    const int lkq  = tid & 3;

    float acc[4][4] = {};

    for (int k0 = 0; k0 < K; k0 += 16) {
        const float4 av = *(const float4*)(A + (size_t)(m0 + lrow) * lda + k0 + lkq * 4);
        const float4 wv = *(const float4*)(W + (size_t)(n0 + lrow) * ldw + k0 + lkq * 4);

        __syncthreads();
        As[lkq * 4 + 0][lrow] = av.x;
        As[lkq * 4 + 1][lrow] = av.y;
        As[lkq * 4 + 2][lrow] = av.z;
        As[lkq * 4 + 3][lrow] = av.w;
        Ws[lkq * 4 + 0][lrow] = wv.x;
        Ws[lkq * 4 + 1][lrow] = wv.y;
        Ws[lkq * 4 + 2][lrow] = wv.z;
        Ws[lkq * 4 + 3][lrow] = wv.w;
        __syncthreads();

#pragma unroll
        for (int k = 0; k < 16; k++) {
            const float4 a = *(const float4*)&As[k][ty * 4];
            const float4 w = *(const float4*)&Ws[k][tx * 4];
            const float avv[4] = {a.x, a.y, a.z, a.w};
            const float wvv[4] = {w.x, w.y, w.z, w.w};
#pragma unroll
            for (int i = 0; i < 4; i++)
#pragma unroll
                for (int j = 0; j < 4; j++)
                    acc[i][j] += avv[i] * wvv[j];
        }
    }

    const int mbase = m0 + ty * 4;
    const int nbase = n0 + tx * 4;
#pragma unroll
    for (int i = 0; i < 4; i++)
#pragma unroll
        for (int j = 0; j < 4; j++) {
            const int n = nbase + j;
            C0[(size_t)(mbase + i) * ldc + n] = softplus_f(acc[i][j] + bias[n]);
        }
}

// x_proj split-K, single 96-wide column tile (conv computed once per (m,d,kz)):
// A[m][d] = silu(conv_b[d] + sum_k conv_w[d][k] * x[m-3+k][d]).
// grid (M/64, KSPLIT); K slice = D_INNER/KSPLIT = 64. Microtile 4m x 6n.
__global__ __launch_bounds__(256)
void gemm_xproj(const float* __restrict__ xg, const float* __restrict__ conv_w,
                const float* __restrict__ conv_b,
                const float* __restrict__ W, float* __restrict__ part)
{
    __shared__ float As[16][68];
    __shared__ float Ws[16][100];

    const int tid  = threadIdx.x;
    const int tx   = tid & 15;      // n-dir, 6 cols each
    const int ty   = tid >> 4;      // m-dir, 4 rows each
    const int m0   = blockIdx.x * 64;
    const int kz   = blockIdx.y;
    const int lrow = tid >> 2;
    const int lkq  = tid & 3;

    const float4* cw = (const float4*)conv_w;   // cw[d] = taps of channel d
    const float4* cb = (const float4*)conv_b;

    float acc[4][6] = {};
    const int kbeg = kz * (D_INNER / KSPLIT);
    const int kend = kbeg + (D_INNER / KSPLIT);

    const int m = m0 + lrow;
    const int t = m & (SEQLEN - 1);

    for (int k0 = kbeg; k0 < kend; k0 += 16) {
        const int dcol = k0 + lkq * 4;
        // conv + silu for A[m][dcol..dcol+3]
        const float4 w0 = cw[dcol], w1 = cw[dcol + 1], w2 = cw[dcol + 2], w3 = cw[dcol + 3];
        float4 a = cb[dcol >> 2];
        const float* xr = xg + (size_t)m * D_INNER + dcol;
        {
            float4 xk;
            if (t >= 3) { xk = *(const float4*)(xr - 3 * D_INNER);
                a.x += w0.x * xk.x; a.y += w1.x * xk.y; a.z += w2.x * xk.z; a.w += w3.x * xk.w; }
            if (t >= 2) { xk = *(const float4*)(xr - 2 * D_INNER);
                a.x += w0.y * xk.x; a.y += w1.y * xk.y; a.z += w2.y * xk.z; a.w += w3.y * xk.w; }
            if (t >= 1) { xk = *(const float4*)(xr - 1 * D_INNER);
                a.x += w0.z * xk.x; a.y += w1.z * xk.y; a.z += w2.z * xk.z; a.w += w3.z * xk.w; }
            xk = *(const float4*)(xr);
            a.x += w0.w * xk.x; a.y += w1.w * xk.y; a.z += w2.w * xk.z; a.w += w3.w * xk.w;
        }
        const float4 av = make_float4(silu_f(a.x), silu_f(a.y), silu_f(a.z), silu_f(a.w));

        // W rows 0..63 staged by all threads; rows 64..95 by threads < 128
        const float4 wv = *(const float4*)(W + (size_t)lrow * D_INNER + k0 + lkq * 4);
        float4 wv2 = make_float4(0.f, 0.f, 0.f, 0.f);
        if (tid < 128)
            wv2 = *(const float4*)(W + (size_t)(64 + lrow) * D_INNER + k0 + lkq * 4);

        __syncthreads();
        As[lkq * 4 + 0][lrow] = av.x;
        As[lkq * 4 + 1][lrow] = av.y;
        As[lkq * 4 + 2][lrow] = av.z;
        As[lkq * 4 + 3][lrow] = av.w;
        Ws[lkq * 4 + 0][lrow] = wv.x;
        Ws[lkq * 4 + 1][lrow] = wv.y;
        Ws[lkq * 4 + 2][lrow] = wv.z;
        Ws[lkq * 4 + 3][lrow] = wv.w;
        if (tid < 128) {
            Ws[lkq * 4 + 0][64 + lrow] = wv2.x;
            Ws[lkq * 4 + 1][64 + lrow] = wv2.y;
            Ws[lkq * 4 + 2][64 + lrow] = wv2.z;
            Ws[lkq * 4 + 3][64 + lrow] = wv2.w;
        }
        __syncthreads();

#pragma unroll
        for (int k = 0; k < 16; k++) {
            const float4 a4 = *(const float4*)&As[k][ty * 4];
            const float avv[4] = {a4.x, a4.y, a4.z, a4.w};
            float wvv[6];
#pragma unroll
            for (int j = 0; j < 6; j++) wvv[j] = Ws[k][tx * 6 + j];
#pragma unroll
            for (int i = 0; i < 4; i++)
#pragma unroll
                for (int j = 0; j < 6; j++)
                    acc[i][j] += avv[i] * wvv[j];
        }
    }

    const int mbase = m0 + ty * 4;
    const int nbase = tx * 6;
#pragma unroll
    for (int i = 0; i < 4; i++)
#pragma unroll
        for (int j = 0; j < 6; j++)
            part[((size_t)kz * M_TOK + mbase + i) * XDBL_W + nbase + j] = acc[i][j];
}

__global__ __launch_bounds__(256)
void xproj_reduce(const float* __restrict__ part, float* __restrict__ xdbl)
{
    const int i = blockIdx.x * 256 + threadIdx.x;   // M_TOK*XDBL_W
    float s = 0.f;
#pragma unroll 8
    for (int k = 0; k < KSPLIT; k++)
        s += part[(size_t)k * M_TOK * XDBL_W + i];
    xdbl[i] = s;
}

// ---------- chunk-parallel selective scan (CHUNKS=64, CLEN=16) ----------
// u = silu(conv(x)+b) recomputed inline via rolling 4-tap window.
// Phase 1: per-chunk decay product P[n] and zero-init partial state S[n].
// Layout of P/S/H: [b][c][n][d] (d-coalesced).
__global__ __launch_bounds__(256)
void scan_part(const float* __restrict__ delta, const float* __restrict__ xdbl,
               const float* __restrict__ xg, const float* __restrict__ conv_w,
               const float* __restrict__ conv_b, const float* __restrict__ A_log,
               float* __restrict__ P, float* __restrict__ S)
{
    const int g = blockIdx.x * 256 + threadIdx.x;   // 262144 total
    const int d = g & (D_INNER - 1);
    const int c = (g >> 11) & (CHUNKS - 1);
    const int b = g >> 17;

    float An[D_STATE];
#pragma unroll
    for (int n = 0; n < D_STATE; n++)
        An[n] = -__expf(A_log[d * D_STATE + n]);

    const float4 wd = ((const float4*)conv_w)[d];
    const float cb = conv_b[d];

    float p[D_STATE], s[D_STATE];
#pragma unroll
    for (int n = 0; n < D_STATE; n++) { p[n] = 1.f; s[n] = 0.f; }

    const size_t row0 = (size_t)b * SEQLEN + c * CLEN;
    const float* xp = xg + row0 * D_INNER + d;
    float xm3 = 0.f, xm2 = 0.f, xm1 = 0.f;
    if (c > 0) {
        xm3 = xp[-3 * D_INNER];
        xm2 = xp[-2 * D_INNER];
        xm1 = xp[-1 * D_INNER];
    }

#pragma unroll 4
    for (int t = 0; t < CLEN; t++) {
        const size_t row = row0 + t;
        const float xm0 = xp[(size_t)t * D_INNER];
        const float u   = silu_f(cb + wd.x * xm3 + wd.y * xm2 + wd.z * xm1 + wd.w * xm0);
        xm3 = xm2; xm2 = xm1; xm1 = xm0;
        const float dlt  = delta[row * D_INNER + d];
        const float dltu = dlt * u;
        const float4* Bp = (const float4*)(xdbl + row * XDBL_W + DT_RANK);
        const float4 B0 = Bp[0], B1 = Bp[1], B2 = Bp[2], B3 = Bp[3];
        const float Bv[D_STATE] = {B0.x, B0.y, B0.z, B0.w, B1.x, B1.y, B1.z, B1.w,
                                   B2.x, B2.y, B2.z, B2.w, B3.x, B3.y, B3.z, B3.w};
#pragma unroll
        for (int n = 0; n < D_STATE; n++) {
            const float a = __expf(dlt * An[n]);
            s[n] = s[n] * a + dltu * Bv[n];
            p[n] *= a;
        }
    }

    const size_t base = ((size_t)(b * CHUNKS + c) * D_STATE) * D_INNER + d;
#pragma unroll
    for (int n = 0; n < D_STATE; n++) {
        P[base + (size_t)n * D_INNER] = p[n];
        S[base + (size_t)n * D_INNER] = s[n];
    }
}

// Phase 1.5: serial cross-chunk combine per (b,n,d); converts P (in-place!)
// into H = chunk-entry states: H[c] = S[c-1] + P[c-1]*H[c-1], H[0]=0.
__global__ __launch_bounds__(256)
void scan_prefix(float* PH, const float* __restrict__ S)
{
    const int g = blockIdx.x * 256 + threadIdx.x;   // 65536 total
    const int d = g & (D_INNER - 1);
    const int n = (g >> 11) & (D_STATE - 1);
    const int b = g >> 15;

    float h = 0.f;
    for (int c = 0; c < CHUNKS; c++) {
        const size_t idx = ((size_t)(b * CHUNKS + c) * D_STATE + n) * D_INNER + d;
        const float p = PH[idx];
        const float s = S[idx];
        PH[idx] = h;
        h = s + p * h;
    }
}

// Phase 2: load chunk-entry state from H, replay chunk (inline conv for u),
// skip + z-gate, emit y as bf16 hi/lo for out_proj's A operand.
__global__ __launch_bounds__(256)
void scan_apply(const float* __restrict__ delta, const float* __restrict__ xdbl,
                const float* __restrict__ xg, const float* __restrict__ conv_w,
                const float* __restrict__ conv_b, const float* __restrict__ A_log,
                const float* __restrict__ D_skip,
                const float* __restrict__ H,
                const float* __restrict__ z,
                us16* __restrict__ yh, us16* __restrict__ yl)
{
    const int g = blockIdx.x * 256 + threadIdx.x;
    const int d = g & (D_INNER - 1);
    const int c = (g >> 11) & (CHUNKS - 1);
    const int b = g >> 17;

    float An[D_STATE];
#pragma unroll
    for (int n = 0; n < D_STATE; n++)
        An[n] = -__expf(A_log[d * D_STATE + n]);

    const float4 wd = ((const float4*)conv_w)[d];
    const float cb = conv_b[d];

    float st[D_STATE];
    const size_t hbase = ((size_t)(b * CHUNKS + c) * D_STATE) * D_INNER + d;
#pragma unroll
    for (int n = 0; n < D_STATE; n++)
        st[n] = H[hbase + (size_t)n * D_INNER];

    const float Dv = D_skip[d];
    const size_t row0 = (size_t)b * SEQLEN + c * CLEN;
    const float* xp = xg + row0 * D_INNER + d;
    float xm3 = 0.f, xm2 = 0.f, xm1 = 0.f;
    if (c > 0) {
        xm3 = xp[-3 * D_INNER];
        xm2 = xp[-2 * D_INNER];
        xm1 = xp[-1 * D_INNER];
    }

#pragma unroll 4
    for (int t = 0; t < CLEN; t++) {
        const size_t row = row0 + t;
        const float xm0 = xp[(size_t)t * D_INNER];
        const float u   = silu_f(cb + wd.x * xm3 + wd.y * xm2 + wd.z * xm1 + wd.w * xm0);
        xm3 = xm2; xm2 = xm1; xm1 = xm0;
        const float dlt  = delta[row * D_INNER + d];
        const float dltu = dlt * u;
        const float4* Bp = (const float4*)(xdbl + row * XDBL_W + DT_RANK);
        const float4 B0 = Bp[0], B1 = Bp[1], B2 = Bp[2], B3 = Bp[3];
        const float4* Cp = (const float4*)(xdbl + row * XDBL_W + DT_RANK + D_STATE);
        const float4 C0 = Cp[0], C1 = Cp[1], C2 = Cp[2], C3 = Cp[3];
        const float Bv[D_STATE] = {B0.x, B0.y, B0.z, B0.w, B1.x, B1.y, B1.z, B1.w,
                                   B2.x, B2.y, B2.z, B2.w, B3.x, B3.y, B3.z, B3.w};
        const float Cv[D_STATE] = {C0.x, C0.y, C0.z, C0.w, C1.x, C1.y, C1.z, C1.w,
                                   C2.x, C2.y, C2.z, C2.w, C3.x, C3.y, C3.z, C3.w};
        float y = 0.f;
#pragma unroll
        for (int n = 0; n < D_STATE; n++) {
            const float a = __expf(dlt * An[n]);
            st[n] = st[n] * a + dltu * Bv[n];
            y += st[n] * Cv[n];
        }
        const float yv = (y + u * Dv) * silu_f(z[row * D_INNER + d]);
        const us16 h = f2bf(yv);
        yh[row * D_INNER + d] = h;
        yl[row * D_INNER + d] = f2bf(yv - bf2f(h));
    }
}

extern "C" void kernel_launch(void* const* d_in, const int* in_sizes, int n_in,
                              void* d_out, int out_size, void* d_ws, size_t ws_size,
                              hipStream_t stream)
{
    const float* hs         = (const float*)d_in[0];
    const float* in_proj_w  = (const float*)d_in[1];
    const float* conv_w     = (const float*)d_in[2];
    const float* conv_b     = (const float*)d_in[3];
    const float* x_proj_w   = (const float*)d_in[4];
    const float* dt_proj_w  = (const float*)d_in[5];
    const float* dt_proj_b  = (const float*)d_in[6];
    const float* A_log      = (const float*)d_in[7];
    const float* D_skip     = (const float*)d_in[8];
    const float* out_proj_w = (const float*)d_in[9];
    float* out = (float*)d_out;

    // Phase-aliased workspace (89 MB). Liveness:
    //   [ 0-16)  x      (step1 -> scan_apply);  opart lower half (step5-6)
    //   [16-32)  z      (step1 -> scan_apply);  opart upper half (step5-6)
    //   [32-48)  delta  (step3 -> scan_apply)
    //   [48-49)  xdbl   (step2 -> scan_apply)
    //   [49-65)  iwh/iwl (step0->1); Pbuf/H (4a->4c)
    //   [49-75)  part (step2 only, 25.2MB — hs+iw splits dead by then)
    //   [65-81)  hsh/hsl (step0->1); Sbuf (4a->4b); ybh/ybl (4c->5)
    //   [81-89)  owh/owl (step0->5)
    char* base = (char*)d_ws;
    const size_t MB = 1u << 20;
    float* xbuf  = (float*)(base);
    float* zbuf  = (float*)(base + 16 * MB);
    float* opart = (float*)(base);             // 32MB over x+z (dead after scan)
    float* dbuf  = (float*)(base + 32 * MB);   // delta
    float* xdbl  = (float*)(base + 48 * MB);
    us16*  iwh   = (us16*)(base + 49 * MB);
    us16*  iwl   = (us16*)(base + 57 * MB);
    float* part  = (float*)(base + 49 * MB);   // x_proj partials 25.2MB (iw+hs dead)
    float* Pbuf  = (float*)(base + 49 * MB);   // scan P/H (part dead)
    us16*  hsh   = (us16*)(base + 65 * MB);
    us16*  hsl   = (us16*)(base + 69 * MB);
    float* Sbuf  = (float*)(base + 65 * MB);   // scan S (hs dead)
    us16*  ybh   = (us16*)(base + 65 * MB);    // y hi (S dead after prefix)
    us16*  ybl   = (us16*)(base + 73 * MB);
    us16*  owh   = (us16*)(base + 81 * MB);
    us16*  owl   = (us16*)(base + 85 * MB);

    const dim3 blk(256);

    // 0. one fused split: hs + in_proj_w + out_proj_w -> bf16 hi/lo
    split_all<<<8192, blk, 0, stream>>>(hs, in_proj_w, out_proj_w,
                                        hsh, hsl, iwh, iwl, owh, owl);

    // 1. in_proj (fused 3-product MFMA, BM=BN=128): xz -> x, z
    gemm_mfma3<128, 1><<<dim3((2 * D_INNER) / 128, M_TOK / 128), blk, 0, stream>>>(
        hsh, hsl, iwh, iwl, D_MODEL, D_MODEL, xbuf, zbuf, D_INNER);

    // 2. x_proj split-K=32, single 96-col tile (conv inlined once) + reduce
    gemm_xproj<<<dim3(M_TOK / 64, KSPLIT), blk, 0, stream>>>(
        xbuf, conv_w, conv_b, x_proj_w, part);
    xproj_reduce<<<(M_TOK * XDBL_W) / 256, blk, 0, stream>>>(part, xdbl);

    // 3. dt_proj + softplus -> delta
    gemm_dt<<<dim3(D_INNER / 64, M_TOK / 64), blk, 0, stream>>>(
        xdbl, XDBL_W, dt_proj_w, DT_RANK, dbuf, D_INNER, dt_proj_b, DT_RANK);

    // 4. chunk-parallel scan (conv inlined): part -> prefix -> apply
    scan_part<<<(BATCH * CHUNKS * D_INNER) / 256, blk, 0, stream>>>(
        dbuf, xdbl, xbuf, conv_w, conv_b, A_log, Pbuf, Sbuf);
    scan_prefix<<<(BATCH * D_STATE * D_INNER) / 256, blk, 0, stream>>>(
        Pbuf, Sbuf);
    scan_apply<<<(BATCH * CHUNKS * D_INNER) / 256, blk, 0, stream>>>(
        dbuf, xdbl, xbuf, conv_w, conv_b, A_log, D_skip, Pbuf, zbuf, ybh, ybl);

    // 5. out_proj (fused 3-product MFMA, BM=BN=128, split-K=4 -> 512 blocks) + add4
    gemm_mfma3<128, 2><<<dim3(D_MODEL / 128, M_TOK / 128, OSPLIT), blk, 0, stream>>>(
        ybh, ybl, owh, owl, D_INNER, D_INNER / OSPLIT, opart, nullptr, D_MODEL);
    add4_kernel<<<(M_TOK * D_MODEL) / 1024, blk, 0, stream>>>(opart, out);
}